// Round 5
// baseline (439.301 us; speedup 1.0000x reference)
//
#include <hip/hip_runtime.h>
#include <math.h>

// Problem: activations [N=8, C=64, D=32, H=64, W=64] fp32, BFP blocks of 16
// along C (stride D*H*W = 131072 elems = 512 KiB), mantissa = 7.
// R4 post-mortem: nt load+store gained 6.5us (426.1 -> 419.6).
// R5 experiment (one variable): regular cached LOADS (input may be
// LLC-resident from the harness restore), keep nt STORES (write-once output
// should not pollute LLC). If neutral -> kernel at pattern-BW ceiling.
#define CH_STRIDE 131072   // D*H*W elements
#define SPATIAL4  32768    // CH_STRIDE / 4 (float4 groups per (n,c) plane)
#define BLK       16       // channels per BFP block

typedef float fvec4 __attribute__((ext_vector_type(4)));

__global__ __launch_bounds__(256)
void bfp_quant_kernel(const float* __restrict__ in, float* __restrict__ out) {
    const int tid   = blockIdx.x * 256 + threadIdx.x;
    const int lane  = threadIdx.x & 63;
    const int sp    = lane & 15;
    const int ch2   = lane >> 4;
    const int wid   = tid >> 6;          // global wave id, 0..65535
    const int chunk = wid & 2047;        // sp4 chunk within plane (2048 = SPATIAL4/16)
    const int nb    = wid >> 11;         // (n*4 + channel_block), 0..31
    const int sp4   = (chunk << 4) + sp;

    const long base = (long)nb * (BLK * (long)CH_STRIDE)
                    + (long)(ch2 * 4) * CH_STRIDE
                    + (long)sp4 * 4;
    const fvec4* __restrict__ ip = (const fvec4*)(in  + base);
    fvec4*       __restrict__ op = (fvec4*)(out + base);

    const fvec4 v0 = ip[0];
    const fvec4 v1 = ip[SPATIAL4];
    const fvec4 v2 = ip[2 * SPATIAL4];
    const fvec4 v3 = ip[3 * SPATIAL4];

    // per-thread max over its 4 channels, per spatial component
    float mx = fmaxf(fmaxf(fabsf(v0.x), fabsf(v1.x)), fmaxf(fabsf(v2.x), fabsf(v3.x)));
    float my = fmaxf(fmaxf(fabsf(v0.y), fabsf(v1.y)), fmaxf(fabsf(v2.y), fabsf(v3.y)));
    float mz = fmaxf(fmaxf(fabsf(v0.z), fabsf(v1.z)), fmaxf(fabsf(v2.z), fabsf(v3.z)));
    float mw = fmaxf(fmaxf(fabsf(v0.w), fabsf(v1.w)), fmaxf(fabsf(v2.w), fabsf(v3.w)));

    // butterfly across the 4 channel-quads (lanes xor 16, xor 32)
    mx = fmaxf(mx, __shfl_xor(mx, 16, 64));
    my = fmaxf(my, __shfl_xor(my, 16, 64));
    mz = fmaxf(mz, __shfl_xor(mz, 16, 64));
    mw = fmaxf(mw, __shfl_xor(mw, 16, 64));
    mx = fmaxf(mx, __shfl_xor(mx, 32, 64));
    my = fmaxf(my, __shfl_xor(my, 32, 64));
    mz = fmaxf(mz, __shfl_xor(mz, 32, 64));
    mw = fmaxf(mw, __shfl_xor(mw, 32, 64));

    // shared_exp = e-1 (frexp: max = f*2^e, f in [0.5,1)); quantum = 2^(e-7)
    int ex, ey, ez, ew;
    (void)frexpf(mx, &ex); (void)frexpf(my, &ey);
    (void)frexpf(mz, &ez); (void)frexpf(mw, &ew);
    const float qx = ldexpf(1.0f, ex - 7), rx = ldexpf(1.0f, 7 - ex);
    const float qy = ldexpf(1.0f, ey - 7), ry = ldexpf(1.0f, 7 - ey);
    const float qz = ldexpf(1.0f, ez - 7), rz = ldexpf(1.0f, 7 - ez);
    const float qw = ldexpf(1.0f, ew - 7), rw = ldexpf(1.0f, 7 - ew);
    const float lim = 127.0f;   // 2^mantissa - 1; max==0 case falls out (rint(0)=0)

    fvec4 o;
    o.x = fminf(fmaxf(rintf(v0.x * rx), -lim), lim) * qx;
    o.y = fminf(fmaxf(rintf(v0.y * ry), -lim), lim) * qy;
    o.z = fminf(fmaxf(rintf(v0.z * rz), -lim), lim) * qz;
    o.w = fminf(fmaxf(rintf(v0.w * rw), -lim), lim) * qw;
    __builtin_nontemporal_store(o, op);
    o.x = fminf(fmaxf(rintf(v1.x * rx), -lim), lim) * qx;
    o.y = fminf(fmaxf(rintf(v1.y * ry), -lim), lim) * qy;
    o.z = fminf(fmaxf(rintf(v1.z * rz), -lim), lim) * qz;
    o.w = fminf(fmaxf(rintf(v1.w * rw), -lim), lim) * qw;
    __builtin_nontemporal_store(o, op + SPATIAL4);
    o.x = fminf(fmaxf(rintf(v2.x * rx), -lim), lim) * qx;
    o.y = fminf(fmaxf(rintf(v2.y * ry), -lim), lim) * qy;
    o.z = fminf(fmaxf(rintf(v2.z * rz), -lim), lim) * qz;
    o.w = fminf(fmaxf(rintf(v2.w * rw), -lim), lim) * qw;
    __builtin_nontemporal_store(o, op + 2 * SPATIAL4);
    o.x = fminf(fmaxf(rintf(v3.x * rx), -lim), lim) * qx;
    o.y = fminf(fmaxf(rintf(v3.y * ry), -lim), lim) * qy;
    o.z = fminf(fmaxf(rintf(v3.z * rz), -lim), lim) * qz;
    o.w = fminf(fmaxf(rintf(v3.w * rw), -lim), lim) * qw;
    __builtin_nontemporal_store(o, op + 3 * SPATIAL4);
}

extern "C" void kernel_launch(void* const* d_in, const int* in_sizes, int n_in,
                              void* d_out, int out_size, void* d_ws, size_t ws_size,
                              hipStream_t stream) {
    const float* in  = (const float*)d_in[0];
    float*       out = (float*)d_out;
    // 64Mi elements / 16 per thread = 4Mi threads = 16384 blocks of 256
    bfp_quant_kernel<<<16384, 256, 0, stream>>>(in, out);
}

// Round 6
// 420.038 us; speedup vs baseline: 1.0459x; 1.0459x over previous
//
#include <hip/hip_runtime.h>
#include <math.h>

// Problem: activations [N=8, C=64, D=32, H=64, W=64] fp32, BFP blocks of 16
// along C (stride D*H*W = 131072 elems = 512 KiB), mantissa = 7.
//
// Final config = R4 (best measured): nontemporal loads AND stores.
// Evidence trail:
//   R1 (cached, 16xf4/thread)      426.3 us
//   R2 (cached, shuffle-reduce)    426.1 us  -> structure-invariant: BW-bound
//   R4 (nt load + nt store)        419.6 us  <- best
//   R5 (cached load + nt store)    439.3 us
// Harness fills alone vary 161.9-174.2 us run-to-run (+-10 us noise on the
// fixed ~340 us of reset traffic in the timed region). Kernel-attributable
// time ~75-105 us vs a 537 MB / 6.5 TB/s = ~82 us pattern floor: roofline.
#define CH_STRIDE 131072   // D*H*W elements
#define SPATIAL4  32768    // CH_STRIDE / 4 (float4 groups per (n,c) plane)
#define BLK       16       // channels per BFP block

typedef float fvec4 __attribute__((ext_vector_type(4)));

__global__ __launch_bounds__(256)
void bfp_quant_kernel(const float* __restrict__ in, float* __restrict__ out) {
    const int tid   = blockIdx.x * 256 + threadIdx.x;
    const int lane  = threadIdx.x & 63;
    const int sp    = lane & 15;
    const int ch2   = lane >> 4;
    const int wid   = tid >> 6;          // global wave id, 0..65535
    const int chunk = wid & 2047;        // sp4 chunk within plane (2048 = SPATIAL4/16)
    const int nb    = wid >> 11;         // (n*4 + channel_block), 0..31
    const int sp4   = (chunk << 4) + sp;

    const long base = (long)nb * (BLK * (long)CH_STRIDE)
                    + (long)(ch2 * 4) * CH_STRIDE
                    + (long)sp4 * 4;
    const fvec4* __restrict__ ip = (const fvec4*)(in  + base);
    fvec4*       __restrict__ op = (fvec4*)(out + base);

    const fvec4 v0 = __builtin_nontemporal_load(ip);
    const fvec4 v1 = __builtin_nontemporal_load(ip + SPATIAL4);
    const fvec4 v2 = __builtin_nontemporal_load(ip + 2 * SPATIAL4);
    const fvec4 v3 = __builtin_nontemporal_load(ip + 3 * SPATIAL4);

    // per-thread max over its 4 channels, per spatial component
    float mx = fmaxf(fmaxf(fabsf(v0.x), fabsf(v1.x)), fmaxf(fabsf(v2.x), fabsf(v3.x)));
    float my = fmaxf(fmaxf(fabsf(v0.y), fabsf(v1.y)), fmaxf(fabsf(v2.y), fabsf(v3.y)));
    float mz = fmaxf(fmaxf(fabsf(v0.z), fabsf(v1.z)), fmaxf(fabsf(v2.z), fabsf(v3.z)));
    float mw = fmaxf(fmaxf(fabsf(v0.w), fabsf(v1.w)), fmaxf(fabsf(v2.w), fabsf(v3.w)));

    // butterfly across the 4 channel-quads (lanes xor 16, xor 32)
    mx = fmaxf(mx, __shfl_xor(mx, 16, 64));
    my = fmaxf(my, __shfl_xor(my, 16, 64));
    mz = fmaxf(mz, __shfl_xor(mz, 16, 64));
    mw = fmaxf(mw, __shfl_xor(mw, 16, 64));
    mx = fmaxf(mx, __shfl_xor(mx, 32, 64));
    my = fmaxf(my, __shfl_xor(my, 32, 64));
    mz = fmaxf(mz, __shfl_xor(mz, 32, 64));
    mw = fmaxf(mw, __shfl_xor(mw, 32, 64));

    // shared_exp = e-1 (frexp: max = f*2^e, f in [0.5,1)); quantum = 2^(e-7)
    int ex, ey, ez, ew;
    (void)frexpf(mx, &ex); (void)frexpf(my, &ey);
    (void)frexpf(mz, &ez); (void)frexpf(mw, &ew);
    const float qx = ldexpf(1.0f, ex - 7), rx = ldexpf(1.0f, 7 - ex);
    const float qy = ldexpf(1.0f, ey - 7), ry = ldexpf(1.0f, 7 - ey);
    const float qz = ldexpf(1.0f, ez - 7), rz = ldexpf(1.0f, 7 - ez);
    const float qw = ldexpf(1.0f, ew - 7), rw = ldexpf(1.0f, 7 - ew);
    const float lim = 127.0f;   // 2^mantissa - 1; max==0 case falls out (rint(0)=0)

    fvec4 o;
    o.x = fminf(fmaxf(rintf(v0.x * rx), -lim), lim) * qx;
    o.y = fminf(fmaxf(rintf(v0.y * ry), -lim), lim) * qy;
    o.z = fminf(fmaxf(rintf(v0.z * rz), -lim), lim) * qz;
    o.w = fminf(fmaxf(rintf(v0.w * rw), -lim), lim) * qw;
    __builtin_nontemporal_store(o, op);
    o.x = fminf(fmaxf(rintf(v1.x * rx), -lim), lim) * qx;
    o.y = fminf(fmaxf(rintf(v1.y * ry), -lim), lim) * qy;
    o.z = fminf(fmaxf(rintf(v1.z * rz), -lim), lim) * qz;
    o.w = fminf(fmaxf(rintf(v1.w * rw), -lim), lim) * qw;
    __builtin_nontemporal_store(o, op + SPATIAL4);
    o.x = fminf(fmaxf(rintf(v2.x * rx), -lim), lim) * qx;
    o.y = fminf(fmaxf(rintf(v2.y * ry), -lim), lim) * qy;
    o.z = fminf(fmaxf(rintf(v2.z * rz), -lim), lim) * qz;
    o.w = fminf(fmaxf(rintf(v2.w * rw), -lim), lim) * qw;
    __builtin_nontemporal_store(o, op + 2 * SPATIAL4);
    o.x = fminf(fmaxf(rintf(v3.x * rx), -lim), lim) * qx;
    o.y = fminf(fmaxf(rintf(v3.y * ry), -lim), lim) * qy;
    o.z = fminf(fmaxf(rintf(v3.z * rz), -lim), lim) * qz;
    o.w = fminf(fmaxf(rintf(v3.w * rw), -lim), lim) * qw;
    __builtin_nontemporal_store(o, op + 3 * SPATIAL4);
}

extern "C" void kernel_launch(void* const* d_in, const int* in_sizes, int n_in,
                              void* d_out, int out_size, void* d_ws, size_t ws_size,
                              hipStream_t stream) {
    const float* in  = (const float*)d_in[0];
    float*       out = (float*)d_out;
    // 64Mi elements / 16 per thread = 4Mi threads = 16384 blocks of 256
    bfp_quant_kernel<<<16384, 256, 0, stream>>>(in, out);
}